// Round 1
// baseline (160.125 us; speedup 1.0000x reference)
//
#include <hip/hip_runtime.h>
#include <math.h>

// Round 7: one wave = one chain, 8 residues/thread.
//  - thread t (lane) owns residues [8t-1 .. 8t+6] (t=0: 3 junk pre-roll steps,
//    reset to identity, then residues 0..6 + init block) -> output floats
//    [72t, 72t+72) of the chain row, 16B-aligned => direct dwordx4 stores.
//  - phase A: 24 serial xf_steps, stashing each partial translation (3 floats).
//  - scan: 6-level Kogge-Stone over 64 lanes (non-commutative compose).
//  - replay: out_k = A.r * stash_k + A.t  (9 FMA, no sincos recompute).
//  - no LDS, no barriers; fully vectorized window loads.

#define LCH 512

struct Xf { float r[9]; float t[3]; };

__device__ __forceinline__ Xf xf_compose(const Xf& A, const Xf& B) {
  Xf C;
#pragma unroll
  for (int i = 0; i < 3; ++i) {
    float a0 = A.r[3*i+0], a1 = A.r[3*i+1], a2 = A.r[3*i+2];
    C.r[3*i+0] = a0*B.r[0] + a1*B.r[3] + a2*B.r[6];
    C.r[3*i+1] = a0*B.r[1] + a1*B.r[4] + a2*B.r[7];
    C.r[3*i+2] = a0*B.r[2] + a1*B.r[5] + a2*B.r[8];
    C.t[i]     = a0*B.t[0] + a1*B.t[1] + a2*B.t[2] + A.t[i];
  }
  return C;
}

// P := P o Delta(theta, len, tau), sparsity-aware (~31 FMA).
__device__ __forceinline__ void xf_step(Xf& P, float theta, float len, float tau) {
  float st, ct, sx, cx;
  __sincosf(theta, &st, &ct);
  __sincosf(tau, &sx, &cx);
  float ux = -ct, uy = cx*st, uz = sx*st;      // delta col0 (= d_local / L)
  float v0 = -st, v1 = -ct*cx, v2 = -ct*sx;    // delta col1; col2 = (0,-sx,cx)
  float c00 = P.r[0]*ux + P.r[1]*uy + P.r[2]*uz;
  float c10 = P.r[3]*ux + P.r[4]*uy + P.r[5]*uz;
  float c20 = P.r[6]*ux + P.r[7]*uy + P.r[8]*uz;
  float c01 = P.r[0]*v0 + P.r[1]*v1 + P.r[2]*v2;
  float c11 = P.r[3]*v0 + P.r[4]*v1 + P.r[5]*v2;
  float c21 = P.r[6]*v0 + P.r[7]*v1 + P.r[8]*v2;
  float c02 = P.r[2]*cx - P.r[1]*sx;
  float c12 = P.r[5]*cx - P.r[4]*sx;
  float c22 = P.r[8]*cx - P.r[7]*sx;
  P.t[0] += len*c00; P.t[1] += len*c10; P.t[2] += len*c20;
  P.r[0]=c00; P.r[1]=c01; P.r[2]=c02;
  P.r[3]=c10; P.r[4]=c11; P.r[5]=c12;
  P.r[6]=c20; P.r[7]=c21; P.r[8]=c22;
}

__device__ __forceinline__ void xf_set_delta(Xf& P, float theta, float len, float tau) {
  float st, ct, sx, cx;
  __sincosf(theta, &st, &ct);
  __sincosf(tau, &sx, &cx);
  float ux = -ct, uy = cx*st, uz = sx*st;
  P.r[0]=ux; P.r[1]=-st;    P.r[2]=0.f;
  P.r[3]=uy; P.r[4]=-ct*cx; P.r[5]=-sx;
  P.r[6]=uz; P.r[7]=-ct*sx; P.r[8]=cx;
  P.t[0]=len*ux; P.t[1]=len*uy; P.t[2]=len*uz;
}

__device__ __forceinline__ void xf_identity(Xf& A) {
  A.r[0]=1.f; A.r[1]=0.f; A.r[2]=0.f;
  A.r[3]=0.f; A.r[4]=1.f; A.r[5]=0.f;
  A.r[6]=0.f; A.r[7]=0.f; A.r[8]=1.f;
  A.t[0]=0.f; A.t[1]=0.f; A.t[2]=0.f;
}

__device__ __forceinline__ Xf xf_shfl_up(const Xf& P, int d) {
  Xf O;
#pragma unroll
  for (int i = 0; i < 9; ++i) O.r[i] = __shfl_up(P.r[i], d, 64);
#pragma unroll
  for (int i = 0; i < 3; ++i) O.t[i] = __shfl_up(P.t[i], d, 64);
  return O;
}

__global__ __launch_bounds__(256) void nerf_r7_kernel(
    const float* __restrict__ g_phi, const float* __restrict__ g_psi,
    const float* __restrict__ g_omg, const float* __restrict__ g_bl,
    const float* __restrict__ g_ba, float* __restrict__ g_out, int nchain)
{
  const int lane  = threadIdx.x & 63;
  const int wave  = threadIdx.x >> 6;
  const int chain = blockIdx.x * 4 + wave;
  if (chain >= nchain) return;

  const float* phir = g_phi + (size_t)chain * LCH;
  const float* psir = g_psi + (size_t)chain * LCH;
  const float* omgr = g_omg + (size_t)chain * LCH;
  const float* blr  = g_bl  + (size_t)chain * (LCH*3);
  const float* bar  = g_ba  + (size_t)chain * (LCH*3);

  const int j8  = 8 * lane;    // first residue + 1 (window is [8t-1 .. 8t+6])
  const int b24 = 24 * lane;   // = 3*(8t)

  // ---- vectorized window loads ----
  // PS/OM window: [8t-1 .. 8t+6]; PH window: phi[8t .. 8t+7] (= phi[r+1] set).
  // BL/BA window: [24t-3 .. 24t+20]. Pre-roll loads clamp to 0 for t=0 (junk,
  // positions preserved; junk feeds only the 3 discarded pre-roll steps).
  float PS[8], OM[8], PH[8], BL[24], BA[24];
  {
    float  e0 = psir[j8 ? j8 - 1 : 0];
    float4 v0 = *(const float4*)(psir + j8);
    float2 v1 = *(const float2*)(psir + j8 + 4);
    float  e7 = psir[j8 + 6];
    PS[0]=e0; PS[1]=v0.x; PS[2]=v0.y; PS[3]=v0.z; PS[4]=v0.w; PS[5]=v1.x; PS[6]=v1.y; PS[7]=e7;
  }
  {
    float  e0 = omgr[j8 ? j8 - 1 : 0];
    float4 v0 = *(const float4*)(omgr + j8);
    float2 v1 = *(const float2*)(omgr + j8 + 4);
    float  e7 = omgr[j8 + 6];
    OM[0]=e0; OM[1]=v0.x; OM[2]=v0.y; OM[3]=v0.z; OM[4]=v0.w; OM[5]=v1.x; OM[6]=v1.y; OM[7]=e7;
  }
  {
    float4 v0 = *(const float4*)(phir + j8);
    float4 v1 = *(const float4*)(phir + j8 + 4);
    PH[0]=v0.x; PH[1]=v0.y; PH[2]=v0.z; PH[3]=v0.w;
    PH[4]=v1.x; PH[5]=v1.y; PH[6]=v1.z; PH[7]=v1.w;
  }
  {
    float  e0  = blr[b24 >= 3 ? b24 - 3 : 0];
    float2 e12 = *(const float2*)(blr + (b24 >= 2 ? b24 - 2 : 0));
    float4 w0 = *(const float4*)(blr + b24);
    float4 w1 = *(const float4*)(blr + b24 + 4);
    float4 w2 = *(const float4*)(blr + b24 + 8);
    float4 w3 = *(const float4*)(blr + b24 + 12);
    float4 w4 = *(const float4*)(blr + b24 + 16);
    float  e23 = blr[b24 + 20];
    BL[0]=e0;   BL[1]=e12.x; BL[2]=e12.y;
    BL[3]=w0.x; BL[4]=w0.y;  BL[5]=w0.z;  BL[6]=w0.w;
    BL[7]=w1.x; BL[8]=w1.y;  BL[9]=w1.z;  BL[10]=w1.w;
    BL[11]=w2.x; BL[12]=w2.y; BL[13]=w2.z; BL[14]=w2.w;
    BL[15]=w3.x; BL[16]=w3.y; BL[17]=w3.z; BL[18]=w3.w;
    BL[19]=w4.x; BL[20]=w4.y; BL[21]=w4.z; BL[22]=w4.w;
    BL[23]=e23;
  }
  {
    float  e0  = bar[b24 >= 3 ? b24 - 3 : 0];
    float2 e12 = *(const float2*)(bar + (b24 >= 2 ? b24 - 2 : 0));
    float4 w0 = *(const float4*)(bar + b24);
    float4 w1 = *(const float4*)(bar + b24 + 4);
    float4 w2 = *(const float4*)(bar + b24 + 8);
    float4 w3 = *(const float4*)(bar + b24 + 12);
    float4 w4 = *(const float4*)(bar + b24 + 16);
    float  e23 = bar[b24 + 20];
    BA[0]=e0;   BA[1]=e12.x; BA[2]=e12.y;
    BA[3]=w0.x; BA[4]=w0.y;  BA[5]=w0.z;  BA[6]=w0.w;
    BA[7]=w1.x; BA[8]=w1.y;  BA[9]=w1.z;  BA[10]=w1.w;
    BA[11]=w2.x; BA[12]=w2.y; BA[13]=w2.z; BA[14]=w2.w;
    BA[15]=w3.x; BA[16]=w3.y; BA[17]=w3.z; BA[18]=w3.w;
    BA[19]=w4.x; BA[20]=w4.y; BA[21]=w4.z; BA[22]=w4.w;
    BA[23]=e23;
  }

  // ---- Phase A: 24 serial steps, stash partial translations ----
  // residue m (window-relative), sub-step a: a=0 (N): theta=ba1 L=bl2 tau=psi
  //   a=1 (CA): theta=ba2 L=bl0 tau=omega;  a=2 (C): theta=ba0 L=bl1 tau=phi[r+1]
  Xf P;
  float sx[24], sy[24], sz[24];
#pragma unroll
  for (int k = 0; k < 24; ++k) {
    const int m = k / 3, a = k - 3*m;   // compile-time after unroll
    float th, ln, ta;
    if (a == 0)      { th = BA[3*m+1]; ln = BL[3*m+2]; ta = PS[m]; }
    else if (a == 1) { th = BA[3*m+2]; ln = BL[3*m+0]; ta = OM[m]; }
    else             { th = BA[3*m+0]; ln = BL[3*m+1]; ta = PH[m]; }
    if (k == 0) xf_set_delta(P, th, ln, ta);
    else        xf_step(P, th, ln, ta);
    sx[k] = P.t[0]; sy[k] = P.t[1]; sz[k] = P.t[2];
    if (k == 2 && lane == 0) xf_identity(P);  // discard t=0 pre-roll
  }

  // ---- intra-wave inclusive scan (non-commutative) ----
#pragma unroll
  for (int d = 1; d < 64; d <<= 1) {
    Xf O = xf_shfl_up(P, d);
    if (lane >= d) P = xf_compose(O, P);
  }
  Xf E = xf_shfl_up(P, 1);   // exclusive (junk for lane 0)

  // ---- prefix transform A = I0 [o E] ----
  Xf A;
  {
    const float ax=17.047f, ay=14.099f, az=3.625f;
    const float bx_=16.967f, by_=12.784f, bz_=4.338f;
    const float cx_=15.685f, cy_=12.755f, cz_=5.133f;
    float abx=bx_-ax, aby=by_-ay, abz=bz_-az;
    float vx=cx_-bx_, vy=cy_-by_, vz=cz_-bz_;
    float vn = sqrtf(vx*vx+vy*vy+vz*vz) + 1e-8f;
    vx/=vn; vy/=vn; vz/=vn;
    float crx = aby*vz - abz*vy;
    float cry = abz*vx - abx*vz;
    float crz = abx*vy - aby*vx;
    float cn = sqrtf(crx*crx+cry*cry+crz*crz) + 1e-8f;
    float nx=crx/cn, ny=cry/cn, nz=crz/cn;
    float mx = ny*vz - nz*vy;
    float my = nz*vx - nx*vz;
    float mz = nx*vy - ny*vx;
    A.r[0]=vx; A.r[1]=mx; A.r[2]=nx;
    A.r[3]=vy; A.r[4]=my; A.r[5]=ny;
    A.r[6]=vz; A.r[7]=mz; A.r[8]=nz;
    A.t[0]=cx_; A.t[1]=cy_; A.t[2]=cz_;
  }
  if (lane > 0) A = xf_compose(A, E);

  // ---- replay: pure matvec on stashed translations ----
  float out[72];
#pragma unroll
  for (int k = 0; k < 24; ++k) {
    out[3*k+0] = A.r[0]*sx[k] + A.r[1]*sy[k] + A.r[2]*sz[k] + A.t[0];
    out[3*k+1] = A.r[3]*sx[k] + A.r[4]*sy[k] + A.r[5]*sz[k] + A.t[1];
    out[3*k+2] = A.r[6]*sx[k] + A.r[7]*sy[k] + A.r[8]*sz[k] + A.t[2];
  }
  if (lane == 0) {   // init block replaces the 3 junk pre-roll outputs
    out[0]=17.047f; out[1]=14.099f; out[2]=3.625f;
    out[3]=16.967f; out[4]=12.784f; out[5]=4.338f;
    out[6]=15.685f; out[7]=12.755f; out[8]=5.133f;
  }

  // ---- direct aligned dwordx4 stores: floats [72t, 72t+72) of chain row ----
  float* orow = g_out + (size_t)chain * 4608 + 72 * lane;
#pragma unroll
  for (int q = 0; q < 18; ++q) {
    float4 v;
    v.x = out[4*q+0]; v.y = out[4*q+1]; v.z = out[4*q+2]; v.w = out[4*q+3];
    *(float4*)(orow + 4*q) = v;
  }
}

extern "C" void kernel_launch(void* const* d_in, const int* in_sizes, int n_in,
                              void* d_out, int out_size, void* d_ws, size_t ws_size,
                              hipStream_t stream) {
  const float* phi = (const float*)d_in[0];
  const float* psi = (const float*)d_in[1];
  const float* omg = (const float*)d_in[2];
  const float* bl  = (const float*)d_in[3];
  const float* ba  = (const float*)d_in[4];
  float* out = (float*)d_out;
  const int B = in_sizes[0] / LCH;          // 4096 chains
  const int blocks = (B + 3) / 4;           // 4 chains (4 waves) per block
  hipLaunchKernelGGL(nerf_r7_kernel, dim3(blocks), dim3(256), 0, stream,
                     phi, psi, omg, bl, ba, out, B);
}

// Round 3
// 153.353 us; speedup vs baseline: 1.0442x; 1.0442x over previous
//
#include <hip/hip_runtime.h>
#include <math.h>

// Round 9: R8 design resubmitted WITHOUT sched_barrier(0) (suspected container
// killer: 42 scheduling-region splits in a ~2000-inst unrolled body explode
// the scheduler; this problem has a documented history of source-dependent
// container failures). Pressure containment now relies on __launch_bounds__
// (256,2) alone: allocator budget 256 VGPR/wave, natural allocation ~140-200,
// no spill. Architecture unchanged from R7/R8:
//  - one wave = one chain, 8 residues/thread, windows [8t-1 .. 8t+6]
//  - phase A: 24 serial xf_steps, stash partial translations (72 floats)
//  - 6-level Kogge-Stone wave scan (non-commutative compose)
//  - replay fused into the float4 store loop (no out[72] array)
//  - no LDS, no barriers, fully vectorized loads + dwordx4 stores.

#define LCH 512

struct Xf { float r[9]; float t[3]; };

__device__ __forceinline__ Xf xf_compose(const Xf& A, const Xf& B) {
  Xf C;
#pragma unroll
  for (int i = 0; i < 3; ++i) {
    float a0 = A.r[3*i+0], a1 = A.r[3*i+1], a2 = A.r[3*i+2];
    C.r[3*i+0] = a0*B.r[0] + a1*B.r[3] + a2*B.r[6];
    C.r[3*i+1] = a0*B.r[1] + a1*B.r[4] + a2*B.r[7];
    C.r[3*i+2] = a0*B.r[2] + a1*B.r[5] + a2*B.r[8];
    C.t[i]     = a0*B.t[0] + a1*B.t[1] + a2*B.t[2] + A.t[i];
  }
  return C;
}

// P := P o Delta(theta, len, tau), sparsity-aware (~31 FMA).
__device__ __forceinline__ void xf_step(Xf& P, float theta, float len, float tau) {
  float st, ct, sx, cx;
  __sincosf(theta, &st, &ct);
  __sincosf(tau, &sx, &cx);
  float ux = -ct, uy = cx*st, uz = sx*st;      // delta col0 (= d_local / L)
  float v0 = -st, v1 = -ct*cx, v2 = -ct*sx;    // delta col1; col2 = (0,-sx,cx)
  float c00 = P.r[0]*ux + P.r[1]*uy + P.r[2]*uz;
  float c10 = P.r[3]*ux + P.r[4]*uy + P.r[5]*uz;
  float c20 = P.r[6]*ux + P.r[7]*uy + P.r[8]*uz;
  float c01 = P.r[0]*v0 + P.r[1]*v1 + P.r[2]*v2;
  float c11 = P.r[3]*v0 + P.r[4]*v1 + P.r[5]*v2;
  float c21 = P.r[6]*v0 + P.r[7]*v1 + P.r[8]*v2;
  float c02 = P.r[2]*cx - P.r[1]*sx;
  float c12 = P.r[5]*cx - P.r[4]*sx;
  float c22 = P.r[8]*cx - P.r[7]*sx;
  P.t[0] += len*c00; P.t[1] += len*c10; P.t[2] += len*c20;
  P.r[0]=c00; P.r[1]=c01; P.r[2]=c02;
  P.r[3]=c10; P.r[4]=c11; P.r[5]=c12;
  P.r[6]=c20; P.r[7]=c21; P.r[8]=c22;
}

__device__ __forceinline__ void xf_set_delta(Xf& P, float theta, float len, float tau) {
  float st, ct, sx, cx;
  __sincosf(theta, &st, &ct);
  __sincosf(tau, &sx, &cx);
  float ux = -ct, uy = cx*st, uz = sx*st;
  P.r[0]=ux; P.r[1]=-st;    P.r[2]=0.f;
  P.r[3]=uy; P.r[4]=-ct*cx; P.r[5]=-sx;
  P.r[6]=uz; P.r[7]=-ct*sx; P.r[8]=cx;
  P.t[0]=len*ux; P.t[1]=len*uy; P.t[2]=len*uz;
}

__device__ __forceinline__ void xf_identity(Xf& A) {
  A.r[0]=1.f; A.r[1]=0.f; A.r[2]=0.f;
  A.r[3]=0.f; A.r[4]=1.f; A.r[5]=0.f;
  A.r[6]=0.f; A.r[7]=0.f; A.r[8]=1.f;
  A.t[0]=0.f; A.t[1]=0.f; A.t[2]=0.f;
}

__device__ __forceinline__ Xf xf_shfl_up(const Xf& P, int d) {
  Xf O;
#pragma unroll
  for (int i = 0; i < 9; ++i) O.r[i] = __shfl_up(P.r[i], d, 64);
#pragma unroll
  for (int i = 0; i < 3; ++i) O.t[i] = __shfl_up(P.t[i], d, 64);
  return O;
}

// replay matvec for output float f (0..71) of this thread; f compile-time.
#define REP(f) (A.r[3*((f)%3)+0]*sx[(f)/3] + A.r[3*((f)%3)+1]*sy[(f)/3] \
              + A.r[3*((f)%3)+2]*sz[(f)/3] + A.t[(f)%3])

__global__ __launch_bounds__(256, 2) void nerf_r9_kernel(
    const float* __restrict__ g_phi, const float* __restrict__ g_psi,
    const float* __restrict__ g_omg, const float* __restrict__ g_bl,
    const float* __restrict__ g_ba, float* __restrict__ g_out, int nchain)
{
  const int lane  = threadIdx.x & 63;
  const int wave  = threadIdx.x >> 6;
  const int chain = blockIdx.x * 4 + wave;
  if (chain >= nchain) return;

  const float* phir = g_phi + (size_t)chain * LCH;
  const float* psir = g_psi + (size_t)chain * LCH;
  const float* omgr = g_omg + (size_t)chain * LCH;
  const float* blr  = g_bl  + (size_t)chain * (LCH*3);
  const float* bar  = g_ba  + (size_t)chain * (LCH*3);

  const int j8  = 8 * lane;    // window is residues [8t-1 .. 8t+6]
  const int b24 = 24 * lane;

  // ---- vectorized window loads (t=0 pre-roll clamped; junk discarded) ----
  float PS[8], OM[8], PH[8], BL[24], BA[24];
  {
    float  e0 = psir[j8 ? j8 - 1 : 0];
    float4 v0 = *(const float4*)(psir + j8);
    float2 v1 = *(const float2*)(psir + j8 + 4);
    float  e7 = psir[j8 + 6];
    PS[0]=e0; PS[1]=v0.x; PS[2]=v0.y; PS[3]=v0.z; PS[4]=v0.w; PS[5]=v1.x; PS[6]=v1.y; PS[7]=e7;
  }
  {
    float  e0 = omgr[j8 ? j8 - 1 : 0];
    float4 v0 = *(const float4*)(omgr + j8);
    float2 v1 = *(const float2*)(omgr + j8 + 4);
    float  e7 = omgr[j8 + 6];
    OM[0]=e0; OM[1]=v0.x; OM[2]=v0.y; OM[3]=v0.z; OM[4]=v0.w; OM[5]=v1.x; OM[6]=v1.y; OM[7]=e7;
  }
  {
    float4 v0 = *(const float4*)(phir + j8);
    float4 v1 = *(const float4*)(phir + j8 + 4);
    PH[0]=v0.x; PH[1]=v0.y; PH[2]=v0.z; PH[3]=v0.w;
    PH[4]=v1.x; PH[5]=v1.y; PH[6]=v1.z; PH[7]=v1.w;
  }
  {
    float  e0  = blr[b24 >= 3 ? b24 - 3 : 0];
    float2 e12 = *(const float2*)(blr + (b24 >= 2 ? b24 - 2 : 0));
    float4 w0 = *(const float4*)(blr + b24);
    float4 w1 = *(const float4*)(blr + b24 + 4);
    float4 w2 = *(const float4*)(blr + b24 + 8);
    float4 w3 = *(const float4*)(blr + b24 + 12);
    float4 w4 = *(const float4*)(blr + b24 + 16);
    float  e23 = blr[b24 + 20];
    BL[0]=e0;   BL[1]=e12.x; BL[2]=e12.y;
    BL[3]=w0.x; BL[4]=w0.y;  BL[5]=w0.z;  BL[6]=w0.w;
    BL[7]=w1.x; BL[8]=w1.y;  BL[9]=w1.z;  BL[10]=w1.w;
    BL[11]=w2.x; BL[12]=w2.y; BL[13]=w2.z; BL[14]=w2.w;
    BL[15]=w3.x; BL[16]=w3.y; BL[17]=w3.z; BL[18]=w3.w;
    BL[19]=w4.x; BL[20]=w4.y; BL[21]=w4.z; BL[22]=w4.w;
    BL[23]=e23;
  }
  {
    float  e0  = bar[b24 >= 3 ? b24 - 3 : 0];
    float2 e12 = *(const float2*)(bar + (b24 >= 2 ? b24 - 2 : 0));
    float4 w0 = *(const float4*)(bar + b24);
    float4 w1 = *(const float4*)(bar + b24 + 4);
    float4 w2 = *(const float4*)(bar + b24 + 8);
    float4 w3 = *(const float4*)(bar + b24 + 12);
    float4 w4 = *(const float4*)(bar + b24 + 16);
    float  e23 = bar[b24 + 20];
    BA[0]=e0;   BA[1]=e12.x; BA[2]=e12.y;
    BA[3]=w0.x; BA[4]=w0.y;  BA[5]=w0.z;  BA[6]=w0.w;
    BA[7]=w1.x; BA[8]=w1.y;  BA[9]=w1.z;  BA[10]=w1.w;
    BA[11]=w2.x; BA[12]=w2.y; BA[13]=w2.z; BA[14]=w2.w;
    BA[15]=w3.x; BA[16]=w3.y; BA[17]=w3.z; BA[18]=w3.w;
    BA[19]=w4.x; BA[20]=w4.y; BA[21]=w4.z; BA[22]=w4.w;
    BA[23]=e23;
  }

  // ---- Phase A: 24 serial steps, stash partial translations ----
  // step a of residue m: a=0 (N): theta=ba1 L=bl2 tau=psi
  //   a=1 (CA): theta=ba2 L=bl0 tau=omega;  a=2 (C): theta=ba0 L=bl1 tau=phi[r+1]
  Xf P;
  float sx[24], sy[24], sz[24];
#pragma unroll
  for (int k = 0; k < 24; ++k) {
    const int m = k / 3, a = k - 3*m;   // compile-time after unroll
    float th, ln, ta;
    if (a == 0)      { th = BA[3*m+1]; ln = BL[3*m+2]; ta = PS[m]; }
    else if (a == 1) { th = BA[3*m+2]; ln = BL[3*m+0]; ta = OM[m]; }
    else             { th = BA[3*m+0]; ln = BL[3*m+1]; ta = PH[m]; }
    if (k == 0) xf_set_delta(P, th, ln, ta);
    else        xf_step(P, th, ln, ta);
    sx[k] = P.t[0]; sy[k] = P.t[1]; sz[k] = P.t[2];
    if (k == 2 && lane == 0) xf_identity(P);  // discard t=0 pre-roll
  }

  // ---- intra-wave inclusive scan (non-commutative) ----
#pragma unroll
  for (int d = 1; d < 64; d <<= 1) {
    Xf O = xf_shfl_up(P, d);
    if (lane >= d) P = xf_compose(O, P);
  }
  Xf E = xf_shfl_up(P, 1);   // exclusive (junk for lane 0)

  // ---- prefix transform A = I0 [o E] ----
  Xf A;
  {
    const float ax=17.047f, ay=14.099f, az=3.625f;
    const float bx_=16.967f, by_=12.784f, bz_=4.338f;
    const float cx_=15.685f, cy_=12.755f, cz_=5.133f;
    float abx=bx_-ax, aby=by_-ay, abz=bz_-az;
    float vx=cx_-bx_, vy=cy_-by_, vz=cz_-bz_;
    float vn = sqrtf(vx*vx+vy*vy+vz*vz) + 1e-8f;
    vx/=vn; vy/=vn; vz/=vn;
    float crx = aby*vz - abz*vy;
    float cry = abz*vx - abx*vz;
    float crz = abx*vy - aby*vx;
    float cn = sqrtf(crx*crx+cry*cry+crz*crz) + 1e-8f;
    float nx=crx/cn, ny=cry/cn, nz=crz/cn;
    float mx = ny*vz - nz*vy;
    float my = nz*vx - nx*vz;
    float mz = nx*vy - ny*vx;
    A.r[0]=vx; A.r[1]=mx; A.r[2]=nx;
    A.r[3]=vy; A.r[4]=my; A.r[5]=ny;
    A.r[6]=vz; A.r[7]=mz; A.r[8]=nz;
    A.t[0]=cx_; A.t[1]=cy_; A.t[2]=cz_;
  }
  if (lane > 0) A = xf_compose(A, E);

  // ---- fused replay + direct aligned dwordx4 stores ----
  float* orow = g_out + (size_t)chain * 4608 + 72 * lane;
#pragma unroll
  for (int q = 0; q < 18; ++q) {
    float4 v;
    v.x = REP(4*q + 0);
    v.y = REP(4*q + 1);
    v.z = REP(4*q + 2);
    v.w = REP(4*q + 3);
    *(float4*)(orow + 4*q) = v;
  }
  if (lane == 0) {   // init block replaces the 3 junk pre-roll atoms
    float4 i0; i0.x=17.047f; i0.y=14.099f; i0.z=3.625f;  i0.w=16.967f;
    float4 i1; i1.x=12.784f; i1.y=4.338f;  i1.z=15.685f; i1.w=12.755f;
    *(float4*)(orow + 0) = i0;
    *(float4*)(orow + 4) = i1;
    orow[8] = 5.133f;
  }
}

extern "C" void kernel_launch(void* const* d_in, const int* in_sizes, int n_in,
                              void* d_out, int out_size, void* d_ws, size_t ws_size,
                              hipStream_t stream) {
  const float* phi = (const float*)d_in[0];
  const float* psi = (const float*)d_in[1];
  const float* omg = (const float*)d_in[2];
  const float* bl  = (const float*)d_in[3];
  const float* ba  = (const float*)d_in[4];
  float* out = (float*)d_out;
  const int B = in_sizes[0] / LCH;          // 4096 chains
  const int blocks = (B + 3) / 4;           // 4 chains (4 waves) per block
  hipLaunchKernelGGL(nerf_r9_kernel, dim3(blocks), dim3(256), 0, stream,
                     phi, psi, omg, bl, ba, out, B);
}